// Round 1
// baseline (222.511 us; speedup 1.0000x reference)
//
#include <hip/hip_runtime.h>

#define B_ROWS 524288
#define D_DIM 64

// One 16-lane subgroup per row: lane loads float4 -> wave covers 4 rows, 1KB coalesced.
__global__ __launch_bounds__(256) void mcl_kernel(
    const float* __restrict__ x,
    const int* __restrict__ labels,
    const float* __restrict__ lin_w,
    const float* __restrict__ lin_b,
    const float* __restrict__ linear_p,   // (1000,1,3)
    const float* __restrict__ bias_p,     // (1000,3)
    const float* __restrict__ centers,    // (1000,3,1)
    float* __restrict__ out)
{
    const int tid        = blockIdx.x * blockDim.x + threadIdx.x;
    const int lane       = threadIdx.x & 63;
    const int sub        = lane & 15;       // position within the 16-lane row group
    const int rowInWave  = lane >> 4;       // 0..3
    const int waveGlobal = tid >> 6;
    const int totalWaves = (gridDim.x * blockDim.x) >> 6;
    const int rowsPerIter = totalWaves * 4;

    const float4 lw = ((const float4*)lin_w)[sub];  // lin_w fragment, held in regs
    const float  lb = lin_b[0];

    float acc = 0.0f;

    for (int row = waveGlobal * 4 + rowInWave; row < B_ROWS; row += rowsPerIter) {
        const float4 xv = ((const float4*)(x + (size_t)row * D_DIM))[sub];

        float sd = xv.x * lw.x + xv.y * lw.y + xv.z * lw.z + xv.w * lw.w; // dot(x, lin_w)
        float ss = xv.x + xv.y + xv.z + xv.w;                             // sum(x)
        float sq = xv.x * xv.x + xv.y * xv.y + xv.z * xv.z + xv.w * xv.w; // sum(x^2)

        // butterfly within each 16-lane group (xor masks < 16 stay in-group)
        #pragma unroll
        for (int off = 1; off < 16; off <<= 1) {
            sd += __shfl_xor(sd, off, 64);
            ss += __shfl_xor(ss, off, 64);
            sq += __shfl_xor(sq, off, 64);
        }

        if (sub == 0) {
            const int lab = labels[row];
            const float maps = sd + lb;

            const float p0 = linear_p[lab * 3 + 0];
            const float p1 = linear_p[lab * 3 + 1];
            const float p2 = linear_p[lab * 3 + 2];
            const float b0 = bias_p[lab * 3 + 0];
            const float b1 = bias_p[lab * 3 + 1];
            const float b2 = bias_p[lab * 3 + 2];
            const float c0 = centers[lab * 3 + 0];
            const float c1 = centers[lab * 3 + 1];
            const float c2 = centers[lab * 3 + 2];

            const float l0 = maps * p0 + b0;
            const float l1 = maps * p1 + b1;
            const float l2 = maps * p2 + b2;

            const float m  = fmaxf(l0, fmaxf(l1, l2));
            const float e0 = __expf(l0 - m);
            const float e1 = __expf(l1 - m);
            const float e2 = __expf(l2 - m);
            const float denom = e0 + e1 + e2;

            const float dD = (float)D_DIM;
            const float s0 = sq - 2.0f * c0 * ss + dD * c0 * c0;
            const float s1 = sq - 2.0f * c1 * ss + dD * c1 * c1;
            const float s2 = sq - 2.0f * c2 * ss + dD * c2 * c2;

            acc += (e0 * s0 + e1 * s1 + e2 * s2) / denom;
        }
    }

    // wave reduction (acc nonzero only on sub==0 lanes; sum all 64 anyway)
    #pragma unroll
    for (int off = 1; off < 64; off <<= 1)
        acc += __shfl_xor(acc, off, 64);

    __shared__ float waveSums[4];
    if (lane == 0) waveSums[threadIdx.x >> 6] = acc;
    __syncthreads();
    if (threadIdx.x == 0) {
        float s = waveSums[0] + waveSums[1] + waveSums[2] + waveSums[3];
        atomicAdd(out, s * (1.0f / (float)B_ROWS));
    }
}

extern "C" void kernel_launch(void* const* d_in, const int* in_sizes, int n_in,
                              void* d_out, int out_size, void* d_ws, size_t ws_size,
                              hipStream_t stream) {
    const float* x        = (const float*)d_in[0];
    const int*   labels   = (const int*)d_in[1];
    const float* lin_w    = (const float*)d_in[2];
    const float* lin_b    = (const float*)d_in[3];
    const float* linear_p = (const float*)d_in[4];
    const float* bias_p   = (const float*)d_in[5];
    const float* centers  = (const float*)d_in[6];
    float* out = (float*)d_out;

    // Harness poisons d_out with 0xAA before timed replays; zero it ourselves.
    hipMemsetAsync(out, 0, sizeof(float), stream);

    dim3 grid(2048), block(256);
    mcl_kernel<<<grid, block, 0, stream>>>(x, labels, lin_w, lin_b,
                                           linear_p, bias_p, centers, out);
}

// Round 2
// 208.367 us; speedup vs baseline: 1.0679x; 1.0679x over previous
//
#include <hip/hip_runtime.h>

#define B_ROWS 524288
#define D_DIM 64

// 4 lanes per row: each lane loads 4 float4 chunks (16 floats) of its row.
// Per load instruction, each 4-lane row-group covers a contiguous, aligned
// 64 B segment -> full cacheline utilization, 16 lines per wave instruction.
// Row reductions need only 2 butterfly stages (xor 1,2). Epilogue runs
// redundantly on all 4 lanes of a group (same-address table gathers
// broadcast); final sum scaled by 1/4.
__global__ __launch_bounds__(256) void mcl_kernel(
    const float* __restrict__ x,
    const int* __restrict__ labels,
    const float* __restrict__ lin_w,
    const float* __restrict__ lin_b,
    const float* __restrict__ linear_p,   // (1000,1,3)
    const float* __restrict__ bias_p,     // (1000,3)
    const float* __restrict__ centers,    // (1000,3,1)
    float* __restrict__ out)
{
    const int tid        = blockIdx.x * blockDim.x + threadIdx.x;
    const int lane       = threadIdx.x & 63;
    const int sub        = lane & 3;        // position within 4-lane row group
    const int rowInWave  = lane >> 2;       // 0..15
    const int waveGlobal = tid >> 6;
    const int totalWaves = (gridDim.x * blockDim.x) >> 6;
    const int rowsPerIter = totalWaves * 16;

    // This lane's 4 chunks of lin_w (held in regs for the whole kernel)
    const float4 lw0 = ((const float4*)lin_w)[sub + 0];
    const float4 lw1 = ((const float4*)lin_w)[sub + 4];
    const float4 lw2 = ((const float4*)lin_w)[sub + 8];
    const float4 lw3 = ((const float4*)lin_w)[sub + 12];
    const float  lb  = lin_b[0];

    float acc = 0.0f;

    for (int row = waveGlobal * 16 + rowInWave; row < B_ROWS; row += rowsPerIter) {
        const float4* xr = (const float4*)(x + (size_t)row * D_DIM);
        const float4 x0 = xr[sub + 0];
        const float4 x1 = xr[sub + 4];
        const float4 x2 = xr[sub + 8];
        const float4 x3 = xr[sub + 12];

        float sd = x0.x*lw0.x + x0.y*lw0.y + x0.z*lw0.z + x0.w*lw0.w
                 + x1.x*lw1.x + x1.y*lw1.y + x1.z*lw1.z + x1.w*lw1.w
                 + x2.x*lw2.x + x2.y*lw2.y + x2.z*lw2.z + x2.w*lw2.w
                 + x3.x*lw3.x + x3.y*lw3.y + x3.z*lw3.z + x3.w*lw3.w;
        float ss = (x0.x + x0.y + x0.z + x0.w) + (x1.x + x1.y + x1.z + x1.w)
                 + (x2.x + x2.y + x2.z + x2.w) + (x3.x + x3.y + x3.z + x3.w);
        float sq = x0.x*x0.x + x0.y*x0.y + x0.z*x0.z + x0.w*x0.w
                 + x1.x*x1.x + x1.y*x1.y + x1.z*x1.z + x1.w*x1.w
                 + x2.x*x2.x + x2.y*x2.y + x2.z*x2.z + x2.w*x2.w
                 + x3.x*x3.x + x3.y*x3.y + x3.z*x3.z + x3.w*x3.w;

        // 2-stage butterfly within the 4-lane group (all 4 lanes end with totals)
        #pragma unroll
        for (int off = 1; off < 4; off <<= 1) {
            sd += __shfl_xor(sd, off, 64);
            ss += __shfl_xor(ss, off, 64);
            sq += __shfl_xor(sq, off, 64);
        }

        // Epilogue on ALL lanes (4 lanes of a group do identical work; gathers
        // are same-address within the group -> broadcast). Scale by 1/4 at end.
        const int lab = labels[row];
        const float maps = sd + lb;

        const float p0 = linear_p[lab * 3 + 0];
        const float p1 = linear_p[lab * 3 + 1];
        const float p2 = linear_p[lab * 3 + 2];
        const float b0 = bias_p[lab * 3 + 0];
        const float b1 = bias_p[lab * 3 + 1];
        const float b2 = bias_p[lab * 3 + 2];
        const float c0 = centers[lab * 3 + 0];
        const float c1 = centers[lab * 3 + 1];
        const float c2 = centers[lab * 3 + 2];

        const float l0 = maps * p0 + b0;
        const float l1 = maps * p1 + b1;
        const float l2 = maps * p2 + b2;

        const float m  = fmaxf(l0, fmaxf(l1, l2));
        const float e0 = __expf(l0 - m);
        const float e1 = __expf(l1 - m);
        const float e2 = __expf(l2 - m);
        const float denom = e0 + e1 + e2;

        const float dD = (float)D_DIM;
        const float s0 = sq - 2.0f * c0 * ss + dD * c0 * c0;
        const float s1 = sq - 2.0f * c1 * ss + dD * c1 * c1;
        const float s2 = sq - 2.0f * c2 * ss + dD * c2 * c2;

        acc += (e0 * s0 + e1 * s1 + e2 * s2) / denom;
    }

    // wave reduction (each row counted 4x; corrected by 0.25 factor below)
    #pragma unroll
    for (int off = 1; off < 64; off <<= 1)
        acc += __shfl_xor(acc, off, 64);

    __shared__ float waveSums[4];
    if (lane == 0) waveSums[threadIdx.x >> 6] = acc;
    __syncthreads();
    if (threadIdx.x == 0) {
        float s = waveSums[0] + waveSums[1] + waveSums[2] + waveSums[3];
        atomicAdd(out, s * (0.25f / (float)B_ROWS));
    }
}

extern "C" void kernel_launch(void* const* d_in, const int* in_sizes, int n_in,
                              void* d_out, int out_size, void* d_ws, size_t ws_size,
                              hipStream_t stream) {
    const float* x        = (const float*)d_in[0];
    const int*   labels   = (const int*)d_in[1];
    const float* lin_w    = (const float*)d_in[2];
    const float* lin_b    = (const float*)d_in[3];
    const float* linear_p = (const float*)d_in[4];
    const float* bias_p   = (const float*)d_in[5];
    const float* centers  = (const float*)d_in[6];
    float* out = (float*)d_out;

    // Harness poisons d_out with 0xAA before timed replays; zero it ourselves.
    hipMemsetAsync(out, 0, sizeof(float), stream);

    dim3 grid(2048), block(256);
    mcl_kernel<<<grid, block, 0, stream>>>(x, labels, lin_w, lin_b,
                                           linear_p, bias_p, centers, out);
}

// Round 3
// 198.375 us; speedup vs baseline: 1.1217x; 1.0504x over previous
//
#include <hip/hip_runtime.h>

#define B_ROWS 524288
#define D_DIM 64
#define GRID 2048
#define BLOCK 256
// waves total = GRID*BLOCK/64 = 8192; rows per wave-iter = 16 -> rowsPerIter = 131072
#define ROWS_PER_ITER ((GRID * BLOCK / 64) * 16)
#define N_ITERS (B_ROWS / ROWS_PER_ITER)   // = 4, compile-time

// 4 lanes per row: each lane loads 4 float4 chunks (16 floats) of its row.
// 2-stage butterfly for the 3 row reductions; epilogue duplicated across the
// 4 lanes of a group (same-address gathers broadcast); block partial -> d_ws.
__global__ __launch_bounds__(BLOCK) void mcl_main(
    const float* __restrict__ x,
    const int* __restrict__ labels,
    const float* __restrict__ lin_w,
    const float* __restrict__ lin_b,
    const float* __restrict__ linear_p,   // (1000,1,3)
    const float* __restrict__ bias_p,     // (1000,3)
    const float* __restrict__ centers,    // (1000,3,1)
    float* __restrict__ partials)
{
    const int tid        = blockIdx.x * BLOCK + threadIdx.x;
    const int lane       = threadIdx.x & 63;
    const int sub        = lane & 3;        // position within 4-lane row group
    const int rowInWave  = lane >> 2;       // 0..15
    const int waveGlobal = tid >> 6;

    const float4 lw0 = ((const float4*)lin_w)[sub + 0];
    const float4 lw1 = ((const float4*)lin_w)[sub + 4];
    const float4 lw2 = ((const float4*)lin_w)[sub + 8];
    const float4 lw3 = ((const float4*)lin_w)[sub + 12];
    const float  lb  = lin_b[0];

    float acc = 0.0f;
    int row = waveGlobal * 16 + rowInWave;

    #pragma unroll
    for (int it = 0; it < N_ITERS; ++it, row += ROWS_PER_ITER) {
        const float4* xr = (const float4*)(x + (size_t)row * D_DIM);
        const float4 x0 = xr[sub + 0];
        const float4 x1 = xr[sub + 4];
        const float4 x2 = xr[sub + 8];
        const float4 x3 = xr[sub + 12];

        float sd = x0.x*lw0.x + x0.y*lw0.y + x0.z*lw0.z + x0.w*lw0.w
                 + x1.x*lw1.x + x1.y*lw1.y + x1.z*lw1.z + x1.w*lw1.w
                 + x2.x*lw2.x + x2.y*lw2.y + x2.z*lw2.z + x2.w*lw2.w
                 + x3.x*lw3.x + x3.y*lw3.y + x3.z*lw3.z + x3.w*lw3.w;
        float ss = (x0.x + x0.y + x0.z + x0.w) + (x1.x + x1.y + x1.z + x1.w)
                 + (x2.x + x2.y + x2.z + x2.w) + (x3.x + x3.y + x3.z + x3.w);
        float sq = x0.x*x0.x + x0.y*x0.y + x0.z*x0.z + x0.w*x0.w
                 + x1.x*x1.x + x1.y*x1.y + x1.z*x1.z + x1.w*x1.w
                 + x2.x*x2.x + x2.y*x2.y + x2.z*x2.z + x2.w*x2.w
                 + x3.x*x3.x + x3.y*x3.y + x3.z*x3.z + x3.w*x3.w;

        // 2-stage butterfly within the 4-lane group
        #pragma unroll
        for (int off = 1; off < 4; off <<= 1) {
            sd += __shfl_xor(sd, off, 64);
            ss += __shfl_xor(ss, off, 64);
            sq += __shfl_xor(sq, off, 64);
        }

        // Epilogue on all lanes (4-way duplicated; corrected by 0.25 at the end)
        const int lab = labels[row];
        const float maps = sd + lb;

        const float p0 = linear_p[lab * 3 + 0];
        const float p1 = linear_p[lab * 3 + 1];
        const float p2 = linear_p[lab * 3 + 2];
        const float b0 = bias_p[lab * 3 + 0];
        const float b1 = bias_p[lab * 3 + 1];
        const float b2 = bias_p[lab * 3 + 2];
        const float c0 = centers[lab * 3 + 0];
        const float c1 = centers[lab * 3 + 1];
        const float c2 = centers[lab * 3 + 2];

        const float l0 = maps * p0 + b0;
        const float l1 = maps * p1 + b1;
        const float l2 = maps * p2 + b2;

        const float m  = fmaxf(l0, fmaxf(l1, l2));
        const float e0 = __expf(l0 - m);
        const float e1 = __expf(l1 - m);
        const float e2 = __expf(l2 - m);
        const float rdenom = __builtin_amdgcn_rcpf(e0 + e1 + e2);

        const float dD = (float)D_DIM;
        const float s0 = sq - 2.0f * c0 * ss + dD * c0 * c0;
        const float s1 = sq - 2.0f * c1 * ss + dD * c1 * c1;
        const float s2 = sq - 2.0f * c2 * ss + dD * c2 * c2;

        acc += (e0 * s0 + e1 * s1 + e2 * s2) * rdenom;
    }

    // wave reduction (each row counted 4x; corrected below)
    #pragma unroll
    for (int off = 1; off < 64; off <<= 1)
        acc += __shfl_xor(acc, off, 64);

    __shared__ float waveSums[BLOCK / 64];
    if (lane == 0) waveSums[threadIdx.x >> 6] = acc;
    __syncthreads();
    if (threadIdx.x == 0) {
        float s = waveSums[0] + waveSums[1] + waveSums[2] + waveSums[3];
        partials[blockIdx.x] = s;   // plain store; reducer kernel consumes
    }
}

// Single-block finalize: sum GRID partials, scale, overwrite out (no init needed).
__global__ __launch_bounds__(BLOCK) void mcl_finalize(
    const float* __restrict__ partials, float* __restrict__ out)
{
    float acc = 0.0f;
    #pragma unroll
    for (int i = threadIdx.x; i < GRID; i += BLOCK)
        acc += partials[i];

    const int lane = threadIdx.x & 63;
    #pragma unroll
    for (int off = 1; off < 64; off <<= 1)
        acc += __shfl_xor(acc, off, 64);

    __shared__ float waveSums[BLOCK / 64];
    if (lane == 0) waveSums[threadIdx.x >> 6] = acc;
    __syncthreads();
    if (threadIdx.x == 0) {
        float s = waveSums[0] + waveSums[1] + waveSums[2] + waveSums[3];
        out[0] = s * (0.25f / (float)B_ROWS);
    }
}

extern "C" void kernel_launch(void* const* d_in, const int* in_sizes, int n_in,
                              void* d_out, int out_size, void* d_ws, size_t ws_size,
                              hipStream_t stream) {
    const float* x        = (const float*)d_in[0];
    const int*   labels   = (const int*)d_in[1];
    const float* lin_w    = (const float*)d_in[2];
    const float* lin_b    = (const float*)d_in[3];
    const float* linear_p = (const float*)d_in[4];
    const float* bias_p   = (const float*)d_in[5];
    const float* centers  = (const float*)d_in[6];
    float* out      = (float*)d_out;
    float* partials = (float*)d_ws;

    mcl_main<<<dim3(GRID), dim3(BLOCK), 0, stream>>>(
        x, labels, lin_w, lin_b, linear_p, bias_p, centers, partials);
    mcl_finalize<<<dim3(1), dim3(BLOCK), 0, stream>>>(partials, out);
}